// Round 11
// baseline (2469.834 us; speedup 1.0000x reference)
//
#include <hip/hip_runtime.h>
#include <hip/hip_bf16.h>

typedef unsigned short ushort_t;
typedef __attribute__((ext_vector_type(8))) short bf16x8;
typedef __attribute__((ext_vector_type(4))) float f32x4;

// ---------------- problem constants ----------------
constexpr int NU = 100000, N1 = 60000, N2 = 60000;
constexpr int E = 2000000;
constexpr int TOTN = 2 * NU + N1 + N2;  // deg/norm layout: [du1|di1|du2|di2] = 320000
constexpr int NPART = 8;                // XCD partitions (blockIdx % 8 ~ XCD)
constexpr int CH = 2048;                // k_count LDS chunk
constexpr int NCHUNKS = (E + CH - 1) / CH;
constexpr int PSLICE = TOTN / NPART;    // 40000
constexpr int NSUB = 8;                 // k_count subslices
constexpr int SUBS = PSLICE / NSUB;
// k_fill2: sub-major grid so one sub-generation is resident at a time
constexpr int CH2 = 8192;
constexpr int NCH2 = (E + CH2 - 1) / CH2;   // 245
constexpr int NSUB2 = 4;
constexpr int SUBS2 = PSLICE / NSUB2;       // 10000 (per-XCD write-set ~1.5MB < 4MB L2)

__device__ __forceinline__ ushort_t f2bf(float f) {
  unsigned u = __float_as_uint(f);
  u = u + 0x7fffu + ((u >> 16) & 1u);   // round-to-nearest-even
  return (ushort_t)(u >> 16);
}
__device__ __forceinline__ float bf2f(ushort_t v) {
  return __uint_as_float(((unsigned)v) << 16);
}

// ---------------- degree count (LDS chunk + XCD-partitioned subslices) ----------------
__global__ __launch_bounds__(256) void k_count(const int* __restrict__ s1,
                                               const int* __restrict__ d1,
                                               const int* __restrict__ s2,
                                               const int* __restrict__ d2,
                                               int* __restrict__ deg) {
  __shared__ int ls1[CH], ld1[CH], ls2[CH], ld2[CH];
  int part = blockIdx.x % NPART;
  int base = (blockIdx.x / NPART) * CH;
  int n = E - base; if (n > CH) n = CH;
  for (int i = threadIdx.x; i < n; i += 256) {
    ls1[i] = s1[base + i];
    ld1[i] = d1[base + i];
    ls2[i] = s2[base + i];
    ld2[i] = d2[base + i];
  }
  __syncthreads();
  int plo = part * PSLICE;
  for (int sub = 0; sub < NSUB; ++sub) {
    int lo = plo + sub * SUBS, hi = lo + SUBS;
    for (int i = threadIdx.x; i < n; i += 256) {
      int i0 = ls1[i];
      int i1 = NU + ld1[i];
      int i2 = NU + N1 + ls2[i];
      int i3 = 2 * NU + N1 + ld2[i];
      if (i0 >= lo && i0 < hi) atomicAdd(&deg[i0], 1);
      if (i1 >= lo && i1 < hi) atomicAdd(&deg[i1], 1);
      if (i2 >= lo && i2 < hi) atomicAdd(&deg[i2], 1);
      if (i3 >= lo && i3 < hi) atomicAdd(&deg[i3], 1);
    }
    __syncthreads();
  }
}

// ---------------- normalizers ----------------
__global__ __launch_bounds__(256) void k_norm(const int* __restrict__ deg,
                                              float* __restrict__ nrm) {
  int i = blockIdx.x * 256 + threadIdx.x;
  if (i >= TOTN) return;
  int d = deg[i];
  nrm[i] = rsqrtf((float)(d > 1 ? d : 1));
}

// ---------------- batched exclusive prefix scan (4 segments) ----------------
__global__ __launch_bounds__(256) void k_scan(const int* __restrict__ deg,
                                              int* __restrict__ off,
                                              int* __restrict__ cur) {
  __shared__ int wsum[4];
  int seg = blockIdx.x;
  int baseIn, n, baseOut;
  if (seg == 0)      { baseIn = 0;            n = NU; baseOut = 0; }
  else if (seg == 1) { baseIn = NU;           n = N1; baseOut = NU + 1; }
  else if (seg == 2) { baseIn = NU + N1;      n = NU; baseOut = NU + N1 + 2; }
  else               { baseIn = 2 * NU + N1;  n = N2; baseOut = 2 * NU + N1 + 3; }
  const int* in = deg + baseIn;
  int* out = off + baseOut;
  int* curp = cur + baseIn;

  constexpr int ITEMS = 16;
  int t = threadIdx.x, lane = t & 63, wid = t >> 6;
  int carry = 0;
  for (int base = 0; base < n; base += 256 * ITEMS) {
    int vals[ITEMS];
    int lsum = 0;
    int i0 = base + t * ITEMS;
#pragma unroll
    for (int j = 0; j < ITEMS; ++j) {
      int i = i0 + j;
      int v = (i < n) ? in[i] : 0;
      vals[j] = v;
      lsum += v;
    }
    int incl = lsum;
#pragma unroll
    for (int d = 1; d < 64; d <<= 1) {
      int x = __shfl_up(incl, d, 64);
      if (lane >= d) incl += x;
    }
    if (lane == 63) wsum[wid] = incl;
    __syncthreads();
    int woff = 0;
    for (int w = 0; w < wid; ++w) woff += wsum[w];
    int chunkTotal = wsum[0] + wsum[1] + wsum[2] + wsum[3];
    int excl = carry + woff + (incl - lsum);
#pragma unroll
    for (int j = 0; j < ITEMS; ++j) {
      int i = i0 + j;
      if (i < n) { out[i] = excl; curp[i] = excl; }
      excl += vals[j];
    }
    carry += chunkTotal;
    __syncthreads();
  }
  if (t == 0) out[n] = carry;
}

// ---------------- adjacency fill: sub-major grid, direct reads ----------------
// blockIdx = ((sub*NCH2)+chunk)*NPART + part. One sub-generation of blocks is
// resident at a time -> per-XCD live write-set ~1.5MB fits L2, lines fill fully.
__global__ __launch_bounds__(256) void k_fill2(const int* __restrict__ s1,
                                               const int* __restrict__ d1,
                                               const int* __restrict__ s2,
                                               const int* __restrict__ d2,
                                               int* __restrict__ cur,
                                               int2* __restrict__ ae_s1,
                                               int* __restrict__ a_d1,
                                               int2* __restrict__ ae_s2,
                                               int* __restrict__ a_d2) {
  int part = blockIdx.x % NPART;
  int chunk = (blockIdx.x / NPART) % NCH2;
  int sub = blockIdx.x / (NPART * NCH2);
  int lo = part * PSLICE + sub * SUBS2, hi = lo + SUBS2;
  int base = chunk * CH2;
  int end = base + CH2 < E ? base + CH2 : E;
  for (int i = base + threadIdx.x; i < end; i += 256) {
    int a = s1[i], b = d1[i];
    if (a >= lo && a < hi) {
      int pos = atomicAdd(&cur[a], 1);
      ae_s1[pos] = make_int2(b, i);
    }
    int i1 = NU + b;
    if (i1 >= lo && i1 < hi) a_d1[atomicAdd(&cur[i1], 1)] = a;
    int c = s2[i], d = d2[i];
    int i2 = NU + N1 + c;
    if (i2 >= lo && i2 < hi) {
      int pos = atomicAdd(&cur[i2], 1);
      ae_s2[pos] = make_int2(d, i);
    }
    int i3 = 2 * NU + N1 + d;
    if (i3 >= lo && i3 < hi) a_d2[atomicAdd(&cur[i3], 1)] = c;
  }
}

// ---------------- MFMA bf16 GEMM: C[M][N] = rowscale ⊙ (A[M][K] @ W[K][N]) ----------------
__device__ __forceinline__ bf16x8 loadA8(const float* p) {
  float4 lo = *(const float4*)p;
  float4 hi = *(const float4*)(p + 4);
  bf16x8 v;
  v[0] = (short)f2bf(lo.x); v[1] = (short)f2bf(lo.y);
  v[2] = (short)f2bf(lo.z); v[3] = (short)f2bf(lo.w);
  v[4] = (short)f2bf(hi.x); v[5] = (short)f2bf(hi.y);
  v[6] = (short)f2bf(hi.z); v[7] = (short)f2bf(hi.w);
  return v;
}
__device__ __forceinline__ bf16x8 loadA8(const ushort_t* p) {
  return *(const bf16x8*)p;
}

template <typename AT, int K, int N, bool BF16OUT>
__global__ __launch_bounds__(256) void k_gemm(const AT* __restrict__ A,
                                              const float* __restrict__ W,
                                              void* __restrict__ Cv, int M,
                                              const float* __restrict__ rowscale) {
  constexpr int KF = K / 32, NF = N / 16;
  __shared__ __align__(16) ushort_t sW[N * K];
  for (int i = threadIdx.x * 4; i < K * N; i += 1024) {
    float4 w4 = *(const float4*)&W[i];
    int k = i / N, n0 = i % N;
    float wv[4] = {w4.x, w4.y, w4.z, w4.w};
#pragma unroll
    for (int j = 0; j < 4; ++j) {
      int n = n0 + j;
      sW[(n * K + k) ^ ((n & 7) << 3)] = f2bf(wv[j]);
    }
  }
  __syncthreads();

  int w = threadIdx.x >> 6, lane = threadIdx.x & 63;
  int col = lane & 15, kg = lane >> 4;
  int r = blockIdx.x * 64 + w * 16 + col;
  int rA = r < M ? r : M - 1;

  bf16x8 af[KF];
#pragma unroll
  for (int kf = 0; kf < KF; ++kf)
    af[kf] = loadA8(&A[(size_t)rA * K + kf * 32 + kg * 8]);

  f32x4 acc[NF] = {};
#pragma unroll
  for (int nf = 0; nf < NF; ++nf) {
    int n = nf * 16 + col;
#pragma unroll
    for (int kf = 0; kf < KF; ++kf) {
      int idx = (n * K + kf * 32 + kg * 8) ^ ((n & 7) << 3);
      bf16x8 bfrag = *(const bf16x8*)&sW[idx];
      acc[nf] = __builtin_amdgcn_mfma_f32_16x16x32_bf16(af[kf], bfrag, acc[nf], 0, 0, 0);
    }
  }

  int orow = blockIdx.x * 64 + w * 16 + kg * 4;
#pragma unroll
  for (int reg = 0; reg < 4; ++reg) {
    int R = orow + reg;
    if (R >= M) break;
    float sc = rowscale ? rowscale[R] : 1.f;
#pragma unroll
    for (int nf = 0; nf < NF; ++nf) {
      float v = sc * acc[nf][reg];
      size_t o = (size_t)R * N + nf * 16 + col;
      if constexpr (BF16OUT) ((ushort_t*)Cv)[o] = f2bf(v);
      else                   ((float*)Cv)[o] = v;
    }
  }
}

// ---------------- CSR list accumulation (bf16 z, 4 ch/lane, 8-edge unroll) ----------------
__device__ __forceinline__ int adj_idx(int v) { return v; }
__device__ __forceinline__ int adj_idx(int2 v) { return v.x; }

template <int D, typename IdxT>
__device__ __forceinline__ void accum_list(const ushort_t* __restrict__ z,
                                           const IdxT* __restrict__ adj,
                                           int e0, int e1, int l, float4& A) {
  auto addp = [&](uint2 p) {
    A.x += __uint_as_float(p.x << 16);
    A.y += __uint_as_float(p.x & 0xffff0000u);
    A.z += __uint_as_float(p.y << 16);
    A.w += __uint_as_float(p.y & 0xffff0000u);
  };
  int e = e0;
  for (; e + 8 <= e1; e += 8) {
    uint2 p[8];
#pragma unroll
    for (int j = 0; j < 8; ++j)
      p[j] = *(const uint2*)&z[(size_t)adj_idx(adj[e + j]) * D + 4 * l];
#pragma unroll
    for (int j = 0; j < 8; ++j) addp(p[j]);
  }
  for (; e < e1; ++e)
    addp(*(const uint2*)&z[(size_t)adj_idx(adj[e]) * D + 4 * l]);
}

// ---------------- single-list CSR gather (item sides) ----------------
template <int D, bool RELU, bool BF16OUT>
__global__ __launch_bounds__(256) void k_gather(const ushort_t* __restrict__ z,
                                                const int* __restrict__ off,
                                                const int* __restrict__ adj,
                                                const float* __restrict__ ndst,
                                                const float* __restrict__ bias,
                                                void* __restrict__ outv, int nv) {
  constexpr int LPN = D / 4;
  constexpr int NPB = 256 / LPN;
  int t = threadIdx.x;
  int slot = t / LPN, l = t % LPN;
  int v = blockIdx.x * NPB + slot;
  if (v >= nv) return;
  float4 A = {0.f, 0.f, 0.f, 0.f};
  accum_list<D>(z, adj, off[v], off[v + 1], l, A);
  float nd = ndst[v];
  float r0 = nd * A.x + bias[4 * l];
  float r1 = nd * A.y + bias[4 * l + 1];
  float r2 = nd * A.z + bias[4 * l + 2];
  float r3 = nd * A.w + bias[4 * l + 3];
  if constexpr (RELU) {
    r0 = fmaxf(r0, 0.f); r1 = fmaxf(r1, 0.f);
    r2 = fmaxf(r2, 0.f); r3 = fmaxf(r3, 0.f);
  }
  size_t o = (size_t)v * D + 4 * l;
  if constexpr (BF16OUT) {
    uint2 pk;
    pk.x = (unsigned)f2bf(r0) | ((unsigned)f2bf(r1) << 16);
    pk.y = (unsigned)f2bf(r2) | ((unsigned)f2bf(r3) << 16);
    *(uint2*)&((ushort_t*)outv)[o] = pk;
  } else {
    float4 res; res.x = r0; res.y = r1; res.z = r2; res.w = r3;
    *(float4*)&((float*)outv)[o] = res;
  }
}

// ---------------- fused dual-list gather (user side; int2 (adj,eid) lists) ----------------
template <int D, bool RELU>
__global__ __launch_bounds__(256) void k_gather2(const ushort_t* __restrict__ z1,
                                                 const ushort_t* __restrict__ z2,
                                                 const int* __restrict__ off1,
                                                 const int2* __restrict__ ae1,
                                                 const int* __restrict__ off2,
                                                 const int2* __restrict__ ae2,
                                                 const float* __restrict__ nd1,
                                                 const float* __restrict__ nd2,
                                                 const float* __restrict__ b1,
                                                 const float* __restrict__ b2,
                                                 ushort_t* __restrict__ out, int nv) {
  constexpr int LPN = D / 4;
  constexpr int NPB = 256 / LPN;
  int t = threadIdx.x;
  int slot = t / LPN, l = t % LPN;
  int v = blockIdx.x * NPB + slot;
  if (v >= nv) return;
  float4 A = {0.f, 0.f, 0.f, 0.f};
  float4 B = {0.f, 0.f, 0.f, 0.f};
  accum_list<D>(z1, ae1, off1[v], off1[v + 1], l, A);
  accum_list<D>(z2, ae2, off2[v], off2[v + 1], l, B);
  float n1 = nd1[v], n2 = nd2[v];
  float r0 = n1 * A.x + n2 * B.x + b1[4 * l]     + b2[4 * l];
  float r1 = n1 * A.y + n2 * B.y + b1[4 * l + 1] + b2[4 * l + 1];
  float r2 = n1 * A.z + n2 * B.z + b1[4 * l + 2] + b2[4 * l + 2];
  float r3 = n1 * A.w + n2 * B.w + b1[4 * l + 3] + b2[4 * l + 3];
  if constexpr (RELU) {
    r0 = fmaxf(r0, 0.f); r1 = fmaxf(r1, 0.f);
    r2 = fmaxf(r2, 0.f); r3 = fmaxf(r3, 0.f);
  }
  uint2 pk;
  pk.x = (unsigned)f2bf(r0) | ((unsigned)f2bf(r1) << 16);
  pk.y = (unsigned)f2bf(r2) | ((unsigned)f2bf(r3) << 16);
  *(uint2*)&out[(size_t)v * D + 4 * l] = pk;
}

// ---------------- fused projection + CSR scoring: wave per user ----------------
// p = (u64[u] @ Wp)[lane]; out[eid] = dot64(p, ip[adj])
__global__ __launch_bounds__(256) void k_score2(const ushort_t* __restrict__ u64,
                                                const float* __restrict__ Wp,
                                                const float* __restrict__ ip,
                                                const int* __restrict__ off,
                                                const int2* __restrict__ ae,
                                                float* __restrict__ out, int nu) {
  __shared__ float sWp[64 * 64];
  for (int i = threadIdx.x * 4; i < 4096; i += 1024)
    *(float4*)&sWp[i] = *(const float4*)&Wp[i];
  __syncthreads();
  int w = threadIdx.x >> 6, lane = threadIdx.x & 63;
  int u = blockIdx.x * 4 + w;
  if (u >= nu) return;
  float x = bf2f(u64[(size_t)u * 64 + lane]);
  float p = 0.f;
#pragma unroll
  for (int c = 0; c < 64; ++c) {
    float xc = __shfl(x, c, 64);
    p += xc * sWp[c * 64 + lane];
  }
  int e0 = off[u], e1 = off[u + 1];
  int e = e0;
  for (; e + 2 <= e1; e += 2) {
    int2 A = ae[e], B = ae[e + 1];
    float pA = p * ip[(size_t)A.x * 64 + lane];
    float pB = p * ip[(size_t)B.x * 64 + lane];
#pragma unroll
    for (int d = 32; d >= 1; d >>= 1) {
      pA += __shfl_xor(pA, d, 64);
      pB += __shfl_xor(pB, d, 64);
    }
    if (lane == 0) { out[A.y] = pA; out[B.y] = pB; }
  }
  if (e < e1) {
    int2 A = ae[e];
    float pA = p * ip[(size_t)A.x * 64 + lane];
#pragma unroll
    for (int d = 32; d >= 1; d >>= 1) pA += __shfl_xor(pA, d, 64);
    if (lane == 0) out[A.y] = pA;
  }
}

// ---------------- host launch ----------------
extern "C" void kernel_launch(void* const* d_in, const int* in_sizes, int n_in,
                              void* d_out, int out_size, void* d_ws, size_t ws_size,
                              hipStream_t stream) {
  const float* emb_user = (const float*)d_in[0];
  const float* emb_d1   = (const float*)d_in[1];
  const float* emb_d2   = (const float*)d_in[2];
  const float* W_in     = (const float*)d_in[3];
  const float* b_in     = (const float*)d_in[4];
  const float* W_hid    = (const float*)d_in[5];
  const float* b_hid    = (const float*)d_in[6];
  const float* W_out    = (const float*)d_in[7];
  const float* b_out    = (const float*)d_in[8];
  const float* Wp_d1    = (const float*)d_in[9];
  const float* Wp_d2    = (const float*)d_in[10];
  const int* src_d1     = (const int*)d_in[11];
  const int* dst_d1     = (const int*)d_in[12];
  const int* src_d2     = (const int*)d_in[13];
  const int* dst_d2     = (const int*)d_in[14];
  float* out = (float*)d_out;

  char* p = (char*)d_ws;
  auto alloc = [&](size_t bytes) {
    void* r = (void*)p;
    p += (bytes + 15) & ~(size_t)15;
    return r;
  };
  ushort_t* bufU[2] = {(ushort_t*)alloc((size_t)NU * 128 * 2),
                       (ushort_t*)alloc((size_t)NU * 128 * 2)};
  void* bufI1 = alloc((size_t)N1 * 128 * 2);   // bf16[N][128] L0-1 / fp32[N][64] L2
  void* bufI2 = alloc((size_t)N2 * 128 * 2);
  ushort_t* m = (ushort_t*)alloc((size_t)(N1 + N2) * 128 * 2);  // z staging
  float* nrm = (float*)alloc((size_t)TOTN * 4);
  int* deg = (int*)alloc((size_t)TOTN * 4);
  int* off = (int*)alloc((size_t)(TOTN + 4) * 4);
  int* cur = (int*)alloc((size_t)TOTN * 4);
  int2* ae_s1 = (int2*)alloc((size_t)E * 8);
  int* adj_d1 = (int*)alloc((size_t)E * 4);
  int2* ae_s2 = (int2*)alloc((size_t)E * 8);
  int* adj_d2 = (int*)alloc((size_t)E * 4);

  // ws guard: fail soft (absmax) instead of GPU fault if scratch too small
  if ((size_t)(p - (char*)d_ws) > ws_size) return;

  const float* nu1 = nrm;
  const float* ni1 = nrm + NU;
  const float* nu2 = nrm + NU + N1;
  const float* ni2 = nrm + 2 * NU + N1;
  const int* off_u1 = off;
  const int* off_i1 = off + NU + 1;
  const int* off_u2 = off + NU + N1 + 2;
  const int* off_i2 = off + 2 * NU + N1 + 3;

  // ---- graph preprocessing ----
  hipMemsetAsync(deg, 0, (size_t)TOTN * 4, stream);
  k_count<<<NCHUNKS * NPART, 256, 0, stream>>>(src_d1, dst_d1, src_d2, dst_d2, deg);
  k_norm<<<(TOTN + 255) / 256, 256, 0, stream>>>(deg, nrm);
  k_scan<<<4, 256, 0, stream>>>(deg, off, cur);
  k_fill2<<<NSUB2 * NCH2 * NPART, 256, 0, stream>>>(src_d1, dst_d1, src_d2, dst_d2, cur,
                                                    ae_s1, adj_d1, ae_s2, adj_d2);

  ushort_t* mI1 = m;
  ushort_t* mI2 = m + (size_t)N1 * 128;
  ushort_t* mI1h = m;                       // 64-wide variants (L2)
  ushort_t* mI2h = m + (size_t)N1 * 64;
  ushort_t* mU = m;

  // ---- Layer 0 (A = fp32 embeddings, D=128) ----
  k_gemm<float, 128, 128, true><<<(N1 + 63) / 64, 256, 0, stream>>>(emb_d1, W_in + 1 * 128 * 128, mI1, N1, ni1);
  k_gemm<float, 128, 128, true><<<(N2 + 63) / 64, 256, 0, stream>>>(emb_d2, W_in + 3 * 128 * 128, mI2, N2, ni2);
  k_gather2<128, true><<<(NU + 7) / 8, 256, 0, stream>>>(
      mI1, mI2, off_u1, ae_s1, off_u2, ae_s2, nu1, nu2,
      b_in + 1 * 128, b_in + 3 * 128, bufU[0], NU);
  k_gemm<float, 128, 128, true><<<(NU + 63) / 64, 256, 0, stream>>>(emb_user, W_in + 0 * 128 * 128, mU, NU, nu1);
  k_gather<128, true, true><<<(N1 + 7) / 8, 256, 0, stream>>>(
      mU, off_i1, adj_d1, ni1, b_in + 0 * 128, bufI1, N1);
  k_gemm<float, 128, 128, true><<<(NU + 63) / 64, 256, 0, stream>>>(emb_user, W_in + 2 * 128 * 128, mU, NU, nu2);
  k_gather<128, true, true><<<(N2 + 7) / 8, 256, 0, stream>>>(
      mU, off_i2, adj_d2, ni2, b_in + 2 * 128, bufI2, N2);

  // ---- Layer 1 (A = bf16, D=128) ----
  k_gemm<ushort_t, 128, 128, true><<<(N1 + 63) / 64, 256, 0, stream>>>((ushort_t*)bufI1, W_hid + 1 * 128 * 128, mI1, N1, ni1);
  k_gemm<ushort_t, 128, 128, true><<<(N2 + 63) / 64, 256, 0, stream>>>((ushort_t*)bufI2, W_hid + 3 * 128 * 128, mI2, N2, ni2);
  k_gather2<128, true><<<(NU + 7) / 8, 256, 0, stream>>>(
      mI1, mI2, off_u1, ae_s1, off_u2, ae_s2, nu1, nu2,
      b_hid + 1 * 128, b_hid + 3 * 128, bufU[1], NU);
  k_gemm<ushort_t, 128, 128, true><<<(NU + 63) / 64, 256, 0, stream>>>(bufU[0], W_hid + 0 * 128 * 128, mU, NU, nu1);
  k_gather<128, true, true><<<(N1 + 7) / 8, 256, 0, stream>>>(
      mU, off_i1, adj_d1, ni1, b_hid + 0 * 128, bufI1, N1);
  k_gemm<ushort_t, 128, 128, true><<<(NU + 63) / 64, 256, 0, stream>>>(bufU[0], W_hid + 2 * 128 * 128, mU, NU, nu2);
  k_gather<128, true, true><<<(N2 + 7) / 8, 256, 0, stream>>>(
      mU, off_i2, adj_d2, ni2, b_hid + 2 * 128, bufI2, N2);

  // ---- Layer 2 (A = bf16, D=64; no relu; items fp32 for scoring) ----
  k_gemm<ushort_t, 128, 64, true><<<(N1 + 63) / 64, 256, 0, stream>>>((ushort_t*)bufI1, W_out + 1 * 128 * 64, mI1h, N1, ni1);
  k_gemm<ushort_t, 128, 64, true><<<(N2 + 63) / 64, 256, 0, stream>>>((ushort_t*)bufI2, W_out + 3 * 128 * 64, mI2h, N2, ni2);
  k_gather2<64, false><<<(NU + 15) / 16, 256, 0, stream>>>(
      mI1h, mI2h, off_u1, ae_s1, off_u2, ae_s2, nu1, nu2,
      b_out + 1 * 64, b_out + 3 * 64, bufU[0], NU);
  k_gemm<ushort_t, 128, 64, true><<<(NU + 63) / 64, 256, 0, stream>>>(bufU[1], W_out + 0 * 128 * 64, mU, NU, nu1);
  k_gather<64, false, false><<<(N1 + 15) / 16, 256, 0, stream>>>(
      mU, off_i1, adj_d1, ni1, b_out + 0 * 64, bufI1, N1);
  k_gemm<ushort_t, 128, 64, true><<<(NU + 63) / 64, 256, 0, stream>>>(bufU[1], W_out + 2 * 128 * 64, mU, NU, nu2);
  k_gather<64, false, false><<<(N2 + 15) / 16, 256, 0, stream>>>(
      mU, off_i2, adj_d2, ni2, b_out + 2 * 64, bufI2, N2);

  // ---- fused projection + scoring ----
  k_score2<<<(NU + 3) / 4, 256, 0, stream>>>(bufU[0], Wp_d1, (const float*)bufI1,
                                             off_u1, ae_s1, out, NU);
  k_score2<<<(NU + 3) / 4, 256, 0, stream>>>(bufU[0], Wp_d2, (const float*)bufI2,
                                             off_u2, ae_s2, out + E, NU);
}